// Round 7
// baseline (238.848 us; speedup 1.0000x reference)
//
#include <hip/hip_runtime.h>
#include <hip/hip_bf16.h>

typedef __bf16 bf16;
typedef __bf16 bf16x4 __attribute__((ext_vector_type(4)));
typedef __bf16 bf16x8 __attribute__((ext_vector_type(8)));
typedef float f32x4 __attribute__((ext_vector_type(4)));

__device__ __forceinline__ void gload_lds16(const void* g, void* l) {
  __builtin_amdgcn_global_load_lds((__attribute__((address_space(1))) void*)(g),
                                   (__attribute__((address_space(3))) void*)(l), 16, 0, 0);
}
// raw 2^x (v_exp_f32 IS exp2)
__device__ __forceinline__ float fexp2(float x) {
  float r;
  asm volatile("v_exp_f32 %0, %1" : "=v"(r) : "v"(x));
  return r;
}
__device__ __forceinline__ unsigned cvt_pk_bf16(float lo, float hi) {
  unsigned r;
  asm("v_cvt_pk_bf16_f32 %0, %1, %2" : "=v"(r) : "v"(lo), "v"(hi));
  return r;
}
#define S_WAITCNT_VM(n) asm volatile("s_waitcnt vmcnt(" #n ")" ::: "memory")

// ---------------- diagnostic: encode ws_size into output if workspace too small ----
__global__ void k_diag(float* __restrict__ o, float v) { o[threadIdx.x] = v; }

// ---------------- fp32 -> bf16 convert (vectorized) ----------------
__global__ void k_cvt_bf16(const float* __restrict__ x, bf16* __restrict__ y, int n4) {
  int i = blockIdx.x * blockDim.x + threadIdx.x;
  if (i < n4) {
    float4 v = reinterpret_cast<const float4*>(x)[i];
    bf16x4 o = {(bf16)v.x, (bf16)v.y, (bf16)v.z, (bf16)v.w};
    reinterpret_cast<bf16x4*>(y)[i] = o;
  }
}

// ---------------- W (K x N fp32, row-major) -> Wt (N x K bf16) ----------------
__global__ void k_transpose_w(const float* __restrict__ W, bf16* __restrict__ Wt, int K, int N) {
  __shared__ float tile[32][33];
  int kb = blockIdx.x * 32, nb = blockIdx.y * 32;
  int tx = threadIdx.x & 31, ty = threadIdx.x >> 5;
#pragma unroll
  for (int i = 0; i < 32; i += 8)
    tile[ty + i][tx] = W[(size_t)(kb + ty + i) * N + nb + tx];
  __syncthreads();
#pragma unroll
  for (int i = 0; i < 32; i += 8)
    Wt[(size_t)(nb + ty + i) * K + kb + tx] = (bf16)tile[tx][ty + i];
}

// ---------------- V (cols 512..1023 of KVb) -> Vt[b][kvh][HD][S] (bf16) ----------------
__global__ void k_transpose_v(const bf16* __restrict__ KVb, bf16* __restrict__ Vt) {
  __shared__ bf16 tile[32][34];
  constexpr int S = 2048;
  int sb = blockIdx.x * 32, db = blockIdx.y * 32, bh = blockIdx.z;  // bh = b*4+kvh
  int b = bh >> 2, kvh = bh & 3;
  int tx = threadIdx.x & 31, ty = threadIdx.x >> 5;
  const bf16* src = KVb + (size_t)b * S * 1024 + 512 + kvh * 128;
#pragma unroll
  for (int i = 0; i < 32; i += 8)
    tile[ty + i][tx] = src[(size_t)(sb + ty + i) * 1024 + db + tx];
  __syncthreads();
  bf16* dst = Vt + (size_t)bh * 128 * S;
#pragma unroll
  for (int i = 0; i < 32; i += 8)
    dst[(size_t)(db + ty + i) * S + sb + tx] = tile[tx][ty + i];
}

// ---------------- BMxBN bf16 GEMM: half-K-tile phase pipeline, 8 waves ----------------
// C[M,N] = A[M,K] * Bt[N,K]^T.  BK=64 split into 2 k-half phases; LDS = ring of 4
// half-regions (2 dbuf x 2 half, 24 subtiles x 1KiB each).  Per phase: vmcnt(6) [half
// idx P landed; P+1,P+2 in flight] -> barrier -> issue stage(P+3) -> 8 ds_read ->
// 16 MFMA (setprio).  Never drains vmcnt to 0 in steady state (tail: 3, 0).
// Subtile [16r][32c] bf16; content swizzled chunk ^= row&3 (uniform bank spread);
// staged via global_load_lds with inverse-swizzled per-lane global source.
template <int BM, int BN, int WM, int WN, typename OT>
__global__ __launch_bounds__(512) void k_gemm8(const bf16* __restrict__ A, const bf16* __restrict__ Bt,
                                               OT* __restrict__ C, int N, int Kd) {
  constexpr int AS = BM / 16;          // A subtiles per k-half
  constexpr int TS = (BM + BN) / 16;   // total subtiles per k-half (=24)
  __shared__ __align__(16) bf16 sAB[4][TS * 512];
  const int t = threadIdx.x, w = t >> 6, l = t & 63;
  const int lr = l & 15, lk = l >> 4;
  const int gx = gridDim.x, nwg = gx * gridDim.y;
  const int flat = blockIdx.y * gx + blockIdx.x;
  const int vid = (flat & 7) * (nwg >> 3) + (flat >> 3);  // XCD swizzle (nwg%8==0)
  const int m0 = (vid % gx) * BM, n0 = (vid / gx) * BN;
  const int wm = w / WN, wn = w % WN;
  const int srow = l >> 2;
  const int lchunk = (l & 3) ^ ((l >> 2) & 3);                 // inverse swizzle (write side)
  const int rdoff = lr * 64 + ((lk ^ (lr & 3)) << 4);          // swizzled read offset
  const int nkt = Kd >> 6;
  char* lds = (char*)sAB;

  auto stage = [&](int idx) {  // stage half-tile: tile idx>>1, k-half idx&1
    const int kt = idx >> 1, kh = idx & 1;
    const int k0 = (kt << 6) + (kh << 5);
    char* dst = lds + ((((kt & 1) << 1) + kh) * (TS * 1024));
#pragma unroll
    for (int u = 0; u < 3; ++u) {
      const int j = w * 3 + u;
      const bf16* src = (j < AS)
          ? A + (size_t)(m0 + j * 16 + srow) * Kd + k0 + lchunk * 8
          : Bt + (size_t)(n0 + (j - AS) * 16 + srow) * Kd + k0 + lchunk * 8;
      gload_lds16(src, dst + j * 1024);
    }
  };

  f32x4 acc[4][4] = {};
  stage(0); stage(1); stage(2);
  const int PL = 2 * nkt;
  for (int P = 0; P < PL; ++P) {
    const int rem = PL - 1 - P;
    if (rem >= 2) { S_WAITCNT_VM(6); }
    else if (rem == 1) { S_WAITCNT_VM(3); }
    else { S_WAITCNT_VM(0); }
    __builtin_amdgcn_sched_barrier(0);
    __builtin_amdgcn_s_barrier();
    __builtin_amdgcn_sched_barrier(0);
    if (P + 3 < PL) stage(P + 3);  // ring slot (P+3)&3: readers done in phase P-1
    const char* hb = lds + (((((P >> 1) & 1) << 1) + (P & 1)) * (TS * 1024));
    bf16x8 af[4], bfr[4];
#pragma unroll
    for (int i = 0; i < 4; ++i)
      af[i] = *reinterpret_cast<const bf16x8*>(hb + (wm * 4 + i) * 1024 + rdoff);
#pragma unroll
    for (int j = 0; j < 4; ++j)
      bfr[j] = *reinterpret_cast<const bf16x8*>(hb + (AS + wn * 4 + j) * 1024 + rdoff);
    __builtin_amdgcn_s_setprio(1);
#pragma unroll
    for (int i = 0; i < 4; ++i)
#pragma unroll
      for (int j = 0; j < 4; ++j)
        acc[i][j] = __builtin_amdgcn_mfma_f32_16x16x32_bf16(af[i], bfr[j], acc[i][j], 0, 0, 0);
    __builtin_amdgcn_s_setprio(0);
    __builtin_amdgcn_sched_barrier(0);  // pin MFMAs (and their lgkm waits) before next barrier
  }
#pragma unroll
  for (int i = 0; i < 4; ++i)
#pragma unroll
    for (int j = 0; j < 4; ++j)
#pragma unroll
      for (int r = 0; r < 4; ++r) {
        int row = m0 + wm * 64 + i * 16 + lk * 4 + r;
        int col = n0 + wn * 64 + j * 16 + lr;
        if constexpr (sizeof(OT) == 4)
          C[(size_t)row * N + col] = acc[i][j][r];
        else
          C[(size_t)row * N + col] = (bf16)acc[i][j][r];
      }
}

// ---------------- RoPE in place (optionally folds score scale into Q) ----------------
__global__ void k_rope(bf16* __restrict__ X, const float* __restrict__ cs, const float* __restrict__ sn,
                       int nh, int rowstride, float scale, int total) {
  int idx = blockIdx.x * blockDim.x + threadIdx.x;
  if (idx >= total) return;
  int d = idx & 63;
  int th = idx >> 6;
  int h = th % nh;
  int tok = th / nh;
  size_t base = (size_t)tok * rowstride + h * 128;
  float c = cs[tok * 128 + d], s = sn[tok * 128 + d];
  float x1 = (float)X[base + d];
  float x2 = (float)X[base + d + 64];
  X[base + d] = (bf16)((x1 * c - x2 * s) * scale);
  X[base + d + 64] = (bf16)((x2 * c + x1 * s) * scale);
}

// ---------------- causal flash attention, GQA 4:1, swapped-QK in-register softmax ----
// Swapped QK^T: mfma(K,Q) -> lane holds all 16 scores of q-row (q = lane&15);
// softmax = in-lane trees + 2 shfl_xor; P->PV A-frag via cvt_pk + 16 shuffles (no sP LDS).
// LDS 64 KiB -> 2 blocks/CU.
__global__ __launch_bounds__(256) void k_attn(const bf16* __restrict__ Q, const bf16* __restrict__ KV,
                                              const bf16* __restrict__ Vt, bf16* __restrict__ O) {
  constexpr int S = 2048, NH = 16, HD = 128, QSTR = NH * HD, KVSTR = 1024;
  __shared__ __align__(16) bf16 sK[2][64 * 128];
  __shared__ __align__(16) bf16 sV[2][128 * 64];
  const int bid = blockIdx.x;
  const int vid = (bid & 7) * 64 + (bid >> 3);  // XCD swizzle: one (b,kvh) per XCD
  const int p = vid & 15, bh = vid >> 4;
  const int h = bh & 15, b = bh >> 4;
  const int t = threadIdx.x, w = t >> 6, l = t & 63;
  const int lr = l & 15, lk = l >> 4;
  const int kvh = h >> 2;
  const int swz = (lr & 7) << 4;

  const char* kbase = (const char*)(KV + (size_t)b * S * KVSTR + kvh * HD);
  const int krow_l = w * 16 + (l >> 4);
  const int kcol_l = (l & 15) << 4;
  const char* vtbase = (const char*)(Vt + (size_t)(b * 4 + kvh) * HD * S);
  const int vrow_l = w * 32 + (l >> 3);
  const int vcol_l = (l & 7) << 4;
  char* sKb = (char*)sK;
  char* sVb = (char*)sV;
  auto stage = [&](int kvb, int buf) {
#pragma unroll
    for (int c = 0; c < 4; ++c) {
      const int krow = krow_l + c * 4;
      gload_lds16(kbase + (size_t)(kvb + krow) * 2048 + (kcol_l ^ ((krow & 7) << 4)),
                  sKb + buf * 16384 + (w * 4 + c) * 1024);
      const int vrow = vrow_l + c * 8;
      gload_lds16(vtbase + (size_t)vrow * (S * 2) + kvb * 2 + (vcol_l ^ ((vrow & 7) << 4)),
                  sVb + buf * 16384 + (w * 4 + c) * 1024);
    }
  };
  const int fsrc = (l & 48) | (((l >> 4) & 3) << 2);   // lane holding stats of oacc row r=0
  const int sA = (l & 15) | ((l << 1) & 32);           // P-redistribution source lanes
  const int sB = sA | 16;
  const bool sel = (l & 32) != 0;

  for (int seg = 0; seg < 2; ++seg) {
    const int qtl = seg ? (31 - p) : p;
    const int qw = qtl * 64 + w * 16;
    const int ntiles = qtl + 1;
    int cur = 0;
    stage(0, 0);
    const bf16* Qp = Q + (size_t)(b * S + qw + lr) * QSTR + h * HD + lk * 8;
    bf16x8 qf[4];
#pragma unroll
    for (int i = 0; i < 4; ++i) qf[i] = *reinterpret_cast<const bf16x8*>(Qp + i * 32);
    f32x4 oacc[8] = {};
    float mrow = -3e38f, lsum = 0.f;  // stats for q-row (qw + lr), per-lane partial sum
    __syncthreads();
    for (int tt = 0; tt < ntiles; ++tt) {
      const int kvb = tt * 64;
      if (tt + 1 < ntiles) stage(kvb + 64, cur ^ 1);
      const char* sKc = sKb + cur * 16384;
      const char* sVc = sVb + cur * 16384;
      // ---- QK^T swapped: D[kv][q], lane: q = lr, kv = c*16 + lk*4 + r ----
      float pm[4][4];
#pragma unroll
      for (int c = 0; c < 4; ++c) {
        f32x4 s4 = {};
#pragma unroll
        for (int kf = 0; kf < 4; ++kf) {
          bf16x8 kf8 = *reinterpret_cast<const bf16x8*>(
              sKc + (c * 16 + lr) * 256 + (((kf * 64) + (lk << 4)) ^ swz));
          s4 = __builtin_amdgcn_mfma_f32_16x16x32_bf16(kf8, qf[kf], s4, 0, 0, 0);
        }
#pragma unroll
        for (int r = 0; r < 4; ++r) pm[c][r] = s4[r];
      }
      // ---- causal mask: diagonal tile only; mask kv > q ----
      if (tt == ntiles - 1) {
        const int q = qw + lr;
#pragma unroll
        for (int c = 0; c < 4; ++c)
#pragma unroll
          for (int r = 0; r < 4; ++r)
            if (kvb + c * 16 + lk * 4 + r > q) pm[c][r] = -3e38f;
      }
      // ---- defer-max online softmax (row stats in-lane + 2 shuffles) ----
      float m01 = fmaxf(fmaxf(pm[0][0], pm[0][1]), fmaxf(pm[0][2], pm[0][3]));
      float m23 = fmaxf(fmaxf(pm[1][0], pm[1][1]), fmaxf(pm[1][2], pm[1][3]));
      float m45 = fmaxf(fmaxf(pm[2][0], pm[2][1]), fmaxf(pm[2][2], pm[2][3]));
      float m67 = fmaxf(fmaxf(pm[3][0], pm[3][1]), fmaxf(pm[3][2], pm[3][3]));
      float rowmax = fmaxf(fmaxf(m01, m23), fmaxf(m45, m67));
      rowmax = fmaxf(rowmax, __shfl_xor(rowmax, 16));
      rowmax = fmaxf(rowmax, __shfl_xor(rowmax, 32));
      if (__any(rowmax > mrow + 8.f)) {
        float mn = fmaxf(mrow, rowmax);
        float fac = fexp2(mrow - mn);
        mrow = mn;
        lsum *= fac;
        float f0 = __shfl(fac, fsrc), f1 = __shfl(fac, fsrc + 1);
        float f2 = __shfl(fac, fsrc + 2), f3 = __shfl(fac, fsrc + 3);
#pragma unroll
        for (int ch = 0; ch < 8; ++ch) {
          oacc[ch][0] *= f0; oacc[ch][1] *= f1; oacc[ch][2] *= f2; oacc[ch][3] *= f3;
        }
      }
#pragma unroll
      for (int c = 0; c < 4; ++c)
#pragma unroll
        for (int r = 0; r < 4; ++r) pm[c][r] = fexp2(pm[c][r] - mrow);
      lsum += ((pm[0][0] + pm[0][1]) + (pm[0][2] + pm[0][3])) +
              ((pm[1][0] + pm[1][1]) + (pm[1][2] + pm[1][3])) +
              ((pm[2][0] + pm[2][1]) + (pm[2][2] + pm[2][3])) +
              ((pm[3][0] + pm[3][1]) + (pm[3][2] + pm[3][3]));
      // ---- P -> PV A-frags in-register: cvt_pk + shuffle redistribution ----
      unsigned u0l = cvt_pk_bf16(pm[0][0], pm[0][1]), u0h = cvt_pk_bf16(pm[0][2], pm[0][3]);
      unsigned u1l = cvt_pk_bf16(pm[1][0], pm[1][1]), u1h = cvt_pk_bf16(pm[1][2], pm[1][3]);
      unsigned u2l = cvt_pk_bf16(pm[2][0], pm[2][1]), u2h = cvt_pk_bf16(pm[2][2], pm[2][3]);
      unsigned u3l = cvt_pk_bf16(pm[3][0], pm[3][1]), u3h = cvt_pk_bf16(pm[3][2], pm[3][3]);
      unsigned a0l = __shfl(u0l, sA), a0h = __shfl(u0h, sA);
      unsigned a1l = __shfl(u1l, sA), a1h = __shfl(u1h, sA);
      unsigned a2l = __shfl(u2l, sA), a2h = __shfl(u2h, sA);
      unsigned a3l = __shfl(u3l, sA), a3h = __shfl(u3h, sA);
      unsigned b0l = __shfl(u0l, sB), b0h = __shfl(u0h, sB);
      unsigned b1l = __shfl(u1l, sB), b1h = __shfl(u1h, sB);
      unsigned b2l = __shfl(u2l, sB), b2h = __shfl(u2h, sB);
      unsigned b3l = __shfl(u3l, sB), b3h = __shfl(u3h, sB);
      union U8 { unsigned u[4]; bf16x8 v; } pa0, pa1;
      pa0.u[0] = sel ? a1l : a0l;  pa0.u[1] = sel ? a1h : a0h;
      pa0.u[2] = sel ? b1l : b0l;  pa0.u[3] = sel ? b1h : b0h;
      pa1.u[0] = sel ? a3l : a2l;  pa1.u[1] = sel ? a3h : a2h;
      pa1.u[2] = sel ? b3l : b2l;  pa1.u[3] = sel ? b3h : b2h;
      // ---- PV: out[16q][128d] += P[16q][64kv] * V^T ----
#pragma unroll
      for (int ch = 0; ch < 8; ++ch) {
        bf16x8 vf0 = *reinterpret_cast<const bf16x8*>(
            sVc + (ch * 16 + lr) * 128 + ((lk << 4) ^ swz));
        oacc[ch] = __builtin_amdgcn_mfma_f32_16x16x32_bf16(pa0.v, vf0, oacc[ch], 0, 0, 0);
        bf16x8 vf1 = *reinterpret_cast<const bf16x8*>(
            sVc + (ch * 16 + lr) * 128 + ((64 + (lk << 4)) ^ swz));
        oacc[ch] = __builtin_amdgcn_mfma_f32_16x16x32_bf16(pa1.v, vf1, oacc[ch], 0, 0, 0);
      }
      __syncthreads();
      cur ^= 1;
    }
    // final: combine per-lane partial sums across the 4 lk-groups, normalize, write
    lsum += __shfl_xor(lsum, 16);
    lsum += __shfl_xor(lsum, 32);
    float inv = 1.0f / lsum;
    float i0 = __shfl(inv, fsrc), i1 = __shfl(inv, fsrc + 1);
    float i2 = __shfl(inv, fsrc + 2), i3 = __shfl(inv, fsrc + 3);
    bf16* Op = O + (size_t)(b * S + qw) * QSTR + h * HD;
#pragma unroll
    for (int ch = 0; ch < 8; ++ch) {
      Op[(size_t)(lk * 4 + 0) * QSTR + ch * 16 + lr] = (bf16)(oacc[ch][0] * i0);
      Op[(size_t)(lk * 4 + 1) * QSTR + ch * 16 + lr] = (bf16)(oacc[ch][1] * i1);
      Op[(size_t)(lk * 4 + 2) * QSTR + ch * 16 + lr] = (bf16)(oacc[ch][2] * i2);
      Op[(size_t)(lk * 4 + 3) * QSTR + ch * 16 + lr] = (bf16)(oacc[ch][3] * i3);
    }
  }
}

extern "C" void kernel_launch(void* const* d_in, const int* in_sizes, int n_in,
                              void* d_out, int out_size, void* d_ws, size_t ws_size,
                              hipStream_t stream) {
  const float* hs = (const float*)d_in[0];
  // d_in[1] = attention_mask: pure causal, applied analytically
  const float* cosb = (const float*)d_in[2];
  const float* sinb = (const float*)d_in[3];
  const float* Wq = (const float*)d_in[4];
  const float* Wk = (const float*)d_in[5];
  const float* Wv = (const float*)d_in[6];
  const float* Wo = (const float*)d_in[7];
  float* out = (float*)d_out;

  constexpr int B = 2, S = 2048, H = 2048, NH = 16, NKV = 4, HD = 128;
  constexpr int T = B * S;
  constexpr size_t MB = 1024 * 1024;

  // Workspace plan (d_ws 24 MiB; Q/KV/Vt staged inside d_out = 32 MiB):
  //   d_ws[ 0:16M) : Xb (bf16 X), reused as Ob after QKV projections
  //   d_ws[16:24M) : transposed-weight slot: Wqt -> Wkvt -> Wot (serial lifetimes)
  //   d_out[ 0:16M): Qb   d_out[16:24M): KVb   d_out[24:28M): Vt
  const size_t ws_need = 24 * MB;
  if (ws_size < ws_need) {
    k_diag<<<1, 64, 0, stream>>>(out, 1000.0f + (float)(ws_size / MB));
    return;
  }
  bf16* Xb = (bf16*)d_ws;
  bf16* Wt = (bf16*)((char*)d_ws + 16 * MB);
  bf16* Ob = Xb;
  bf16* Qb = (bf16*)d_out;
  bf16* KVb = (bf16*)((char*)d_out + 16 * MB);
  bf16* Vtb = (bf16*)((char*)d_out + 24 * MB);

  k_cvt_bf16<<<T * H / 4 / 256, 256, 0, stream>>>(hs, Xb, T * H / 4);

  // Q projection (grid 256 blocks, full CU fill)
  k_transpose_w<<<dim3(H / 32, NH * HD / 32), 256, 0, stream>>>(Wq, Wt, H, NH * HD);
  k_gemm8<128, 256, 2, 4, bf16><<<dim3(32, 8), 512, 0, stream>>>(Xb, Wt, Qb, NH * HD, H);

  // K|V fused projection (N rows 0..511 = K, 512..1023 = V; grid 128)
  k_transpose_w<<<dim3(H / 32, NKV * HD / 32), 256, 0, stream>>>(Wk, Wt, H, NKV * HD);
  k_transpose_w<<<dim3(H / 32, NKV * HD / 32), 256, 0, stream>>>(Wv, Wt + (size_t)(NKV * HD) * H, H, NKV * HD);
  k_gemm8<256, 128, 4, 2, bf16><<<dim3(16, 8), 512, 0, stream>>>(Xb, Wt, KVb, 1024, H);

  // V -> Vt[b][kvh][HD][S] (V gets no RoPE)
  k_transpose_v<<<dim3(S / 32, HD / 32, B * NKV), 256, 0, stream>>>(KVb, Vtb);

  // RoPE; Q additionally folds log2(e)/sqrt(HD) so QK^T lands in log2 domain
  const float qscale = 0.12751743f;  // log2(e) / sqrt(128)
  k_rope<<<(T * NH * 64) / 256, 256, 0, stream>>>(Qb, cosb, sinb, NH, NH * HD, qscale, T * NH * 64);
  k_rope<<<(T * NKV * 64) / 256, 256, 0, stream>>>(KVb, cosb, sinb, NKV, 1024, 1.0f, T * NKV * 64);

  // Attention: reads Q/K/Vt from d_out, writes Ob into d_ws
  k_attn<<<512, 256, 0, stream>>>(Qb, KVb, Vtb, Ob);

  // O projection: reads only d_ws, writes all of d_out (grid 256)
  k_transpose_w<<<dim3(H / 32, H / 32), 256, 0, stream>>>(Wo, Wt, H, H);
  k_gemm8<128, 256, 2, 4, float><<<dim3(32, 8), 512, 0, stream>>>(Ob, Wt, out, H, H);
}